// Round 10
// baseline (314.685 us; speedup 1.0000x reference)
//
#include <hip/hip_runtime.h>

#define NB   4
#define H_IN 14
#define W_IN 14
#define FIN  32
#define DI   8
#define F    32
#define C    288   // 3*3*32
#define DO   16
#define HO   12
#define WO   12
#define NPOS (NB*HO*WO)   // 576
#define EPS  1e-7f

#define CH   16            // c-chunks
#define CC   (C/CH)        // 18

#define W2_BYTES   ((size_t)F*C*DO*DI*4)       // 4,718,592
#define CENT_BYTES ((size_t)NPOS*F*DO*4)       // 1,179,648
#define PART_BYTES ((size_t)CH*CENT_BYTES)     // 18,874,368 (part1; part2 aliases)
#define OUT1_BYTES CENT_BYTES

// LDS W-tile: row per o = 96 float4 (f*3 stride +2 used, +1 pad) -> conflict-free
// ds_read_b128 across lanes f=0..31 (bank residue (3f+j)%8 covers all 8).
#define WROW 96
#define WTILE (DO*WROW)    // 1536 float4 = 24 KB per buffer

__device__ __forceinline__ float dot8f(const float4 w0, const float4 w1,
                                       const float4 p0, const float4 p1) {
    return w0.x*p0.x + w0.y*p0.y + w0.z*p0.z + w0.w*p0.w
         + w1.x*p1.x + w1.y*p1.y + w1.z*p1.z + w1.w*p1.w;
}

__device__ __forceinline__ int xbase_of(int pos) {
    const int b = pos/(HO*WO), rem = pos%(HO*WO), ho = rem/WO, wo = rem%WO;
    return ((b*H_IN + ho)*W_IN + wo)*FIN*DI;
}

__device__ __forceinline__ int coff_of(int c) {
    const int slab = c >> 5, fin = c & 31;
    const int kh = slab/3, kw = slab%3;
    return (kh*W_IN + kw)*FIN*DI + fin*DI;
}

// stage one 16KB W tile (c) into LDS buffer with swizzle; 4 float4 per thread
__device__ __forceinline__ void stage_w(const float4* __restrict__ W2f4,
                                        float4* __restrict__ buf,
                                        const int c, const int tid) {
    #pragma unroll
    for (int r = 0; r < 4; ++r) {
        const int w = r*256 + tid;          // 0..1023
        const int o = w >> 6, m = w & 63;
        const int f = m >> 1, j = m & 1;
        buf[o*WROW + f*3 + j] = W2f4[(size_t)c*1024 + w];
    }
}

// ---- transpose W[f][c][o][i] -> W2[c][o][f][i] --------------------------------
__global__ __launch_bounds__(256) void kernT(const float* __restrict__ Wt,
                                             float* __restrict__ W2) {
    const int idx4 = blockIdx.x*256 + threadIdx.x;
    const int i2 = idx4 & 1;
    const int f  = (idx4 >> 1) & 31;
    const int o  = (idx4 >> 6) & 15;
    const int c  = idx4 >> 10;
    ((float4*)W2)[idx4] = ((const float4*)Wt)[((size_t)(f*C + c)*DO + o)*2 + i2];
}

// ---- kern1: cent1 sums. thread=(f,pp) x 2 positions; W staged/dbuf in LDS. ----
// writes part1[ch][pos][f][o] (float4)
__global__ __launch_bounds__(256, 3) void kern1n(const float* __restrict__ x,
                                                 const float* __restrict__ W2,
                                                 float* __restrict__ part1)
{
    __shared__ float4 wt[2][WTILE];     // 48 KB
    const int tid = threadIdx.x;
    const int f  = tid & 31;
    const int pp = tid >> 5;            // 0..7
    const int ch = blockIdx.x & (CH-1);
    const int pg = blockIdx.x >> 4;     // 0..35
    const int posA = pg*16 + pp, posB = posA + 8;
    const int baseA = xbase_of(posA), baseB = xbase_of(posB);

    const float4* W2f4 = (const float4*)W2;
    const int c0 = ch*CC;

    stage_w(W2f4, wt[0], c0, tid);

    float accA[DO], accB[DO];
    #pragma unroll
    for (int o = 0; o < DO; ++o) { accA[o] = 0.f; accB[o] = 0.f; }

    __syncthreads();
    #pragma unroll 1
    for (int cl = 0; cl < CC; ++cl) {
        if (cl + 1 < CC) stage_w(W2f4, wt[(cl+1) & 1], c0 + cl + 1, tid);

        const int coff = coff_of(c0 + cl);
        const float4* pxA = (const float4*)(x + baseA + coff);
        const float4* pxB = (const float4*)(x + baseB + coff);
        const float4 a0 = pxA[0], a1 = pxA[1];
        const float4 b0 = pxB[0], b1 = pxB[1];
        const float4* wb = wt[cl & 1] + f*3;

        #pragma unroll
        for (int o = 0; o < DO; ++o) {
            const float4 w0 = wb[o*WROW], w1 = wb[o*WROW + 1];
            accA[o] += dot8f(w0, w1, a0, a1);
            accB[o] += dot8f(w0, w1, b0, b1);
        }
        __syncthreads();
    }

    float4* dA = (float4*)(part1 + ((size_t)(ch*NPOS + posA)*F + f)*DO);
    dA[0] = make_float4(accA[0],  accA[1],  accA[2],  accA[3]);
    dA[1] = make_float4(accA[4],  accA[5],  accA[6],  accA[7]);
    dA[2] = make_float4(accA[8],  accA[9],  accA[10], accA[11]);
    dA[3] = make_float4(accA[12], accA[13], accA[14], accA[15]);
    float4* dB = (float4*)(part1 + ((size_t)(ch*NPOS + posB)*F + f)*DO);
    dB[0] = make_float4(accB[0],  accB[1],  accB[2],  accB[3]);
    dB[1] = make_float4(accB[4],  accB[5],  accB[6],  accB[7]);
    dB[2] = make_float4(accB[8],  accB[9],  accB[10], accB[11]);
    dB[3] = make_float4(accB[12], accB[13], accB[14], accB[15]);
}

// ---- kernO: out1[pos][f][o] = squash(sum_ch part1 / 32); shuffle-only. --------
// part1 layout [k][pos][f][o]; tid = f*16+o; xor masks <16 stay in f-group.
__global__ __launch_bounds__(512) void kernO(const float* __restrict__ part1,
                                             float* __restrict__ out1)
{
    const int pos = blockIdx.x, tid = threadIdx.x;
    float s = 0.f;
    #pragma unroll
    for (int k = 0; k < CH; ++k)
        s += part1[(size_t)(k*NPOS + pos)*512 + tid];
    s *= (1.f/32.f);

    float sn = s*s;
    sn += __shfl_xor(sn, 1);
    sn += __shfl_xor(sn, 2);
    sn += __shfl_xor(sn, 4);
    sn += __shfl_xor(sn, 8);
    const float sc = (sn/(1.f + sn)) * rsqrtf(sn + EPS);
    out1[(size_t)pos*512 + tid] = s * sc;
}

// ---- kern2: thread=(f,pp) x 2 positions; staged/dbuf W; softmax via shuffle. --
// writes part2[ch][pos][f][o] (aliases part1)
__global__ __launch_bounds__(256, 3) void kern2n(const float* __restrict__ x,
                                                 const float* __restrict__ W2,
                                                 const float* __restrict__ out1,
                                                 float* __restrict__ part2)
{
    __shared__ float4 wt[2][WTILE];     // 48 KB
    const int tid = threadIdx.x;
    const int f  = tid & 31;
    const int pp = tid >> 5;            // 0..7
    const int ch = blockIdx.x & (CH-1);
    const int pg = blockIdx.x >> 4;     // 0..35
    const int posA = pg*16 + pp, posB = posA + 8;
    const int baseA = xbase_of(posA), baseB = xbase_of(posB);

    const float4* W2f4 = (const float4*)W2;
    const int c0 = ch*CC;

    stage_w(W2f4, wt[0], c0, tid);

    float o1A[DO], o1B[DO];
    {
        const float4* sA = (const float4*)(out1 + (size_t)posA*512 + f*DO);
        const float4* sB = (const float4*)(out1 + (size_t)posB*512 + f*DO);
        #pragma unroll
        for (int q = 0; q < 4; ++q) {
            const float4 va = sA[q], vb = sB[q];
            o1A[4*q+0] = va.x; o1A[4*q+1] = va.y; o1A[4*q+2] = va.z; o1A[4*q+3] = va.w;
            o1B[4*q+0] = vb.x; o1B[4*q+1] = vb.y; o1B[4*q+2] = vb.z; o1B[4*q+3] = vb.w;
        }
    }

    float accA[DO], accB[DO];
    #pragma unroll
    for (int o = 0; o < DO; ++o) { accA[o] = 0.f; accB[o] = 0.f; }

    __syncthreads();
    #pragma unroll 1
    for (int cl = 0; cl < CC; ++cl) {
        if (cl + 1 < CC) stage_w(W2f4, wt[(cl+1) & 1], c0 + cl + 1, tid);

        const int coff = coff_of(c0 + cl);
        const float4* pxA = (const float4*)(x + baseA + coff);
        const float4* pxB = (const float4*)(x + baseB + coff);
        const float4 a0 = pxA[0], a1 = pxA[1];
        const float4 b0 = pxB[0], b1 = pxB[1];
        const float4* wb = wt[cl & 1] + f*3;

        float predA[DO], predB[DO];
        #pragma unroll
        for (int o = 0; o < DO; ++o) {
            const float4 w0 = wb[o*WROW], w1 = wb[o*WROW + 1];
            predA[o] = dot8f(w0, w1, a0, a1);
            predB[o] = dot8f(w0, w1, b0, b1);
        }

        float agrA = 0.f, agrB = 0.f;
        #pragma unroll
        for (int o = 0; o < DO; ++o) { agrA += predA[o]*o1A[o]; agrB += predB[o]*o1B[o]; }

        // softmax over the 32 f-lanes (xor masks <32 stay within half-wave)
        float mA = agrA, mB = agrB;
        mA = fmaxf(mA, __shfl_xor(mA, 1));  mB = fmaxf(mB, __shfl_xor(mB, 1));
        mA = fmaxf(mA, __shfl_xor(mA, 2));  mB = fmaxf(mB, __shfl_xor(mB, 2));
        mA = fmaxf(mA, __shfl_xor(mA, 4));  mB = fmaxf(mB, __shfl_xor(mB, 4));
        mA = fmaxf(mA, __shfl_xor(mA, 8));  mB = fmaxf(mB, __shfl_xor(mB, 8));
        mA = fmaxf(mA, __shfl_xor(mA, 16)); mB = fmaxf(mB, __shfl_xor(mB, 16));
        const float eA = __expf(agrA - mA), eB = __expf(agrB - mB);
        float sA = eA, sB = eB;
        sA += __shfl_xor(sA, 1);  sB += __shfl_xor(sB, 1);
        sA += __shfl_xor(sA, 2);  sB += __shfl_xor(sB, 2);
        sA += __shfl_xor(sA, 4);  sB += __shfl_xor(sB, 4);
        sA += __shfl_xor(sA, 8);  sB += __shfl_xor(sB, 8);
        sA += __shfl_xor(sA, 16); sB += __shfl_xor(sB, 16);
        const float ccA = eA / sA, ccB = eB / sB;

        #pragma unroll
        for (int o = 0; o < DO; ++o) { accA[o] += ccA*predA[o]; accB[o] += ccB*predB[o]; }
        __syncthreads();
    }

    float4* dA = (float4*)(part2 + ((size_t)(ch*NPOS + posA)*F + f)*DO);
    dA[0] = make_float4(accA[0],  accA[1],  accA[2],  accA[3]);
    dA[1] = make_float4(accA[4],  accA[5],  accA[6],  accA[7]);
    dA[2] = make_float4(accA[8],  accA[9],  accA[10], accA[11]);
    dA[3] = make_float4(accA[12], accA[13], accA[14], accA[15]);
    float4* dB = (float4*)(part2 + ((size_t)(ch*NPOS + posB)*F + f)*DO);
    dB[0] = make_float4(accB[0],  accB[1],  accB[2],  accB[3]);
    dB[1] = make_float4(accB[4],  accB[5],  accB[6],  accB[7]);
    dB[2] = make_float4(accB[8],  accB[9],  accB[10], accB[11]);
    dB[3] = make_float4(accB[12], accB[13], accB[14], accB[15]);
}

// ---- kern3: reduce cent2 partials, squash, store. -----------------------------
__global__ __launch_bounds__(256) void kern3(const float* __restrict__ part2,
                                             float* __restrict__ out)
{
    const int tid = threadIdx.x;
    const int f = tid & 31, p = tid >> 5;
    const int pos = blockIdx.x*8 + p;

    float cent[DO];
    #pragma unroll
    for (int o = 0; o < DO; ++o) cent[o] = 0.f;
    #pragma unroll
    for (int k = 0; k < CH; ++k) {
        const float4* s = (const float4*)(part2 + ((size_t)(k*NPOS + pos)*F + f)*DO);
        #pragma unroll
        for (int q = 0; q < 4; ++q) {
            const float4 v = s[q];
            cent[q*4+0] += v.x; cent[q*4+1] += v.y;
            cent[q*4+2] += v.z; cent[q*4+3] += v.w;
        }
    }
    float sn = 0.f;
    #pragma unroll
    for (int o = 0; o < DO; ++o) sn += cent[o]*cent[o];
    const float sc = (sn/(1.f + sn)) * rsqrtf(sn + EPS);
    float4* dst = (float4*)(out + ((size_t)pos*F + f)*DO);
    dst[0] = make_float4(cent[0]*sc,  cent[1]*sc,  cent[2]*sc,  cent[3]*sc);
    dst[1] = make_float4(cent[4]*sc,  cent[5]*sc,  cent[6]*sc,  cent[7]*sc);
    dst[2] = make_float4(cent[8]*sc,  cent[9]*sc,  cent[10]*sc, cent[11]*sc);
    dst[3] = make_float4(cent[12]*sc, cent[13]*sc, cent[14]*sc, cent[15]*sc);
}

// -------- fp32 single-kernel fallback (if ws too small) ------------------------
__device__ __forceinline__ float dot8(const float4* __restrict__ w,
                                      const float4 p0, const float4 p1) {
    float4 a = w[0], b = w[1];
    return a.x*p0.x + a.y*p0.y + a.z*p0.z + a.w*p0.w
         + b.x*p1.x + b.y*p1.y + b.z*p1.z + b.w*p1.w;
}

__global__ __launch_bounds__(256) void capsule_kernel_f32(
    const float* __restrict__ x, const float* __restrict__ Wt,
    float* __restrict__ out)
{
    __shared__ float patch[C*DI];
    __shared__ float cent[F*DO];
    __shared__ float out1[F*DO];
    __shared__ float agr[F*C];
    __shared__ float scale_s[F];

    const int tid = threadIdx.x;
    const int pos = blockIdx.x;
    const int b   = pos / (HO*WO);
    const int rem = pos % (HO*WO);
    const int ho  = rem / WO;
    const int wo  = rem % WO;

    #pragma unroll
    for (int slab = 0; slab < 9; ++slab) {
        const int kh = slab / 3, kw = slab % 3;
        const float* src = x + (((b*H_IN + ho + kh)*W_IN + (wo + kw))*FIN)*DI;
        patch[slab*256 + tid] = src[tid];
    }
    __syncthreads();

    const float4* pv = (const float4*)patch;

    {
        const int fo0 = tid, fo1 = tid + 256;
        const int f0 = fo0 >> 4, o0 = fo0 & 15;
        const int f1 = fo1 >> 4, o1 = fo1 & 15;
        float acc0 = 0.f, acc1 = 0.f;
        for (int c = 0; c < C; ++c) {
            const float4 p0 = pv[c*2], p1 = pv[c*2+1];
            acc0 += dot8((const float4*)(Wt + ((f0*C + c)*DO + o0)*DI), p0, p1);
            acc1 += dot8((const float4*)(Wt + ((f1*C + c)*DO + o1)*DI), p0, p1);
        }
        cent[fo0] = acc0 * (1.f/32.f);
        cent[fo1] = acc1 * (1.f/32.f);
    }
    __syncthreads();

    if (tid < F) {
        float sn = 0.f;
        #pragma unroll
        for (int o = 0; o < DO; ++o) { float v = cent[tid*DO + o]; sn += v*v; }
        const float sc = (sn/(1.f + sn)) * rsqrtf(sn + EPS);
        #pragma unroll
        for (int o = 0; o < DO; ++o) out1[tid*DO + o] = cent[tid*DO + o] * sc;
    }
    __syncthreads();

    #pragma unroll 1
    for (int r = 0; r < (F*C)/256; ++r) {
        const int pp = tid + 256*r;
        const int f = pp / C, c = pp % C;
        const float4* wrow = (const float4*)(Wt + (f*C + c)*DO*DI);
        const float4 p0 = pv[c*2], p1 = pv[c*2+1];
        float a = 0.f;
        #pragma unroll
        for (int o = 0; o < DO; ++o) a += dot8(wrow + o*2, p0, p1) * out1[f*DO + o];
        agr[pp] = a;
    }
    __syncthreads();

    for (int c = tid; c < C; c += 256) {
        float m = -1e30f;
        #pragma unroll
        for (int f = 0; f < F; ++f) m = fmaxf(m, agr[f*C + c]);
        float s = 0.f;
        #pragma unroll
        for (int f = 0; f < F; ++f) {
            const float e = __expf(agr[f*C + c] - m);
            agr[f*C + c] = e; s += e;
        }
        const float inv = 1.f / s;
        #pragma unroll
        for (int f = 0; f < F; ++f) agr[f*C + c] *= inv;
    }
    __syncthreads();

    {
        const int fo0 = tid, fo1 = tid + 256;
        const int f0 = fo0 >> 4, o0 = fo0 & 15;
        const int f1 = fo1 >> 4, o1 = fo1 & 15;
        float acc0 = 0.f, acc1 = 0.f;
        for (int c = 0; c < C; ++c) {
            const float4 p0 = pv[c*2], p1 = pv[c*2+1];
            acc0 += agr[f0*C + c] * dot8((const float4*)(Wt + ((f0*C + c)*DO + o0)*DI), p0, p1);
            acc1 += agr[f1*C + c] * dot8((const float4*)(Wt + ((f1*C + c)*DO + o1)*DI), p0, p1);
        }
        cent[fo0] = acc0;
        cent[fo1] = acc1;
    }
    __syncthreads();

    if (tid < F) {
        float sn = 0.f;
        #pragma unroll
        for (int o = 0; o < DO; ++o) { float v = cent[tid*DO + o]; sn += v*v; }
        scale_s[tid] = (sn/(1.f + sn)) * rsqrtf(sn + EPS);
    }
    __syncthreads();

    out[pos*(F*DO) + tid]       = cent[tid]       * scale_s[tid >> 4];
    out[pos*(F*DO) + tid + 256] = cent[tid + 256] * scale_s[(tid >> 4) + 16];
}

extern "C" void kernel_launch(void* const* d_in, const int* in_sizes, int n_in,
                              void* d_out, int out_size, void* d_ws, size_t ws_size,
                              hipStream_t stream) {
    const float* x  = (const float*)d_in[0];
    const float* Wt = (const float*)d_in[1];
    float* out = (float*)d_out;

    if (ws_size >= W2_BYTES + PART_BYTES + OUT1_BYTES) {
        float* W2    = (float*)d_ws;
        float* part1 = (float*)((char*)d_ws + W2_BYTES);      // part2 aliases part1
        float* out1  = (float*)((char*)d_ws + W2_BYTES + PART_BYTES);
        kernT<<<(F*C*DO*DI)/4/256, 256, 0, stream>>>(Wt, W2);        // 1152 blocks
        kern1n<<<CH*(NPOS/16), 256, 0, stream>>>(x, W2, part1);      // 576 blocks
        kernO<<<NPOS, 512, 0, stream>>>(part1, out1);                // 576 blocks
        kern2n<<<CH*(NPOS/16), 256, 0, stream>>>(x, W2, out1, part1); // 576 blocks
        kern3<<<NPOS/8, 256, 0, stream>>>(part1, out);               // 72 blocks
    } else {
        capsule_kernel_f32<<<NPOS, 256, 0, stream>>>(x, Wt, out);
    }
}

// Round 11
// 177.644 us; speedup vs baseline: 1.7714x; 1.7714x over previous
//
#include <hip/hip_runtime.h>

#define NB   4
#define H_IN 14
#define W_IN 14
#define FIN  32
#define DI   8
#define F    32
#define C    288   // 3*3*32
#define DO   16
#define HO   12
#define WO   12
#define NPOS (NB*HO*WO)   // 576
#define EPS  1e-7f

#define CH   16            // c-chunks
#define CC   (C/CH)        // 18

#define W2_BYTES   ((size_t)F*C*DO*DI*4)       // 4,718,592
#define CENT_BYTES ((size_t)NPOS*F*DO*4)       // 1,179,648
#define PART_BYTES ((size_t)CH*CENT_BYTES)     // 18,874,368 (part1; part2 aliases)
#define OUT1_BYTES CENT_BYTES

__device__ __forceinline__ float dot8f(const float4 w0, const float4 w1,
                                       const float4 p0, const float4 p1) {
    return w0.x*p0.x + w0.y*p0.y + w0.z*p0.z + w0.w*p0.w
         + w1.x*p1.x + w1.y*p1.y + w1.z*p1.z + w1.w*p1.w;
}

__device__ __forceinline__ int xbase_of(int pos) {
    const int b = pos/(HO*WO), rem = pos%(HO*WO), ho = rem/WO, wo = rem%WO;
    return ((b*H_IN + ho)*W_IN + wo)*FIN*DI;
}

// stage xs[c_local][p][i] for 18 c's x 8 positions (4.6 KB)
__device__ __forceinline__ void stage_x(const float* __restrict__ x,
                                        float (*xs)[8][8],
                                        const int ch, const int pg, const int tid) {
    #pragma unroll
    for (int r = 0; r < 2; ++r) {
        const int idx = r*256 + tid;           // 288 float4 total
        if (idx < CC*16) {
            const int cl = idx >> 4;
            const int p  = (idx & 15) >> 1;
            const int h  = idx & 1;
            const int c  = ch*CC + cl;
            const int slab = c >> 5, fin = c & 31;
            const int kh = slab/3, kw = slab%3;
            const int off = xbase_of(pg*8 + p) + (kh*W_IN + kw)*FIN*DI + fin*DI + h*4;
            const float4 v = *(const float4*)(x + off);
            *(float4*)&xs[cl][p][h*4] = v;
        }
    }
}

// ---- transpose W[f][c][o][i] -> W2[c][o][f][i] --------------------------------
__global__ __launch_bounds__(256) void kernT(const float* __restrict__ Wt,
                                             float* __restrict__ W2) {
    const int idx4 = blockIdx.x*256 + threadIdx.x;
    const int i2 = idx4 & 1;
    const int f  = (idx4 >> 1) & 31;
    const int o  = (idx4 >> 6) & 15;
    const int c  = idx4 >> 10;
    ((float4*)W2)[idx4] = ((const float4*)Wt)[((size_t)(f*C + c)*DO + o)*2 + i2];
}

// ---- kern1: cent1 partials. thread=(f, o-pair), 8 positions from LDS. ---------
// writes part1[ch][pos][o][f]  (R9-proven structure, untouched)
__global__ __launch_bounds__(256, 4) void kern1n(const float* __restrict__ x,
                                                 const float* __restrict__ W2,
                                                 float* __restrict__ part1)
{
    __shared__ float xs[CC][8][8];
    const int tid = threadIdx.x;
    const int f  = tid & 31;
    const int og = tid >> 5;          // 0..7
    const int o0 = 2*og, o1 = o0 + 1;
    const int ch = blockIdx.x & (CH-1);
    const int pg = blockIdx.x >> 4;   // 0..71

    stage_x(x, xs, ch, pg, tid);
    __syncthreads();

    const float4* W2f4 = (const float4*)W2;
    float acc0[8], acc1[8];
    #pragma unroll
    for (int p = 0; p < 8; ++p) { acc0[p] = 0.f; acc1[p] = 0.f; }

    #pragma unroll 1
    for (int cl = 0; cl < CC; ++cl) {
        const int c = ch*CC + cl;
        const float4* wp = W2f4 + (size_t)c*1024 + f*2;
        const float4 w00 = wp[o0*64], w01 = wp[o0*64 + 1];
        const float4 w10 = wp[o1*64], w11 = wp[o1*64 + 1];
        #pragma unroll
        for (int p = 0; p < 8; ++p) {
            const float4 a  = *(const float4*)&xs[cl][p][0];
            const float4 bq = *(const float4*)&xs[cl][p][4];
            acc0[p] += dot8f(w00, w01, a, bq);
            acc1[p] += dot8f(w10, w11, a, bq);
        }
    }
    #pragma unroll
    for (int p = 0; p < 8; ++p) {
        const size_t base = ((size_t)(ch*NPOS + pg*8 + p))*DO;
        part1[(base + o0)*F + f] = acc0[p];
        part1[(base + o1)*F + f] = acc1[p];
    }
}

// ---- kernO: out1[pos][f][o] = squash(sum_ch part1 / 32). (R9-proven) ----------
__global__ __launch_bounds__(512) void kernO(const float* __restrict__ part1,
                                             float* __restrict__ out1)
{
    __shared__ float red[512];
    const int pos = blockIdx.x, tid = threadIdx.x;
    const int f = tid & 31, o = tid >> 5;

    float s = 0.f;
    #pragma unroll
    for (int k = 0; k < CH; ++k)
        s += part1[(size_t)(k*NPOS + pos)*512 + tid];
    s *= (1.f/32.f);

    red[tid] = s*s;
    __syncthreads();
    if (tid < 256) red[tid] += red[tid + 256];
    __syncthreads();
    if (tid < 128) red[tid] += red[tid + 128];
    __syncthreads();
    if (tid < 64)  red[tid] += red[tid + 64];
    __syncthreads();
    if (tid < 32) {
        const float sn = red[tid] + red[tid + 32];
        red[tid] = (sn/(1.f + sn)) * rsqrtf(sn + EPS);
    }
    __syncthreads();
    out1[(size_t)pos*512 + f*DO + o] = s * red[f];
}

// ---- kern2: thread=(f, o-pair) like kern1 (zero W redundancy); softmax via ----
// per-c LDS round-trip. writes part2[ch][pos][o][f] (aliases part1).
__global__ __launch_bounds__(256) void kern2n(const float* __restrict__ x,
                                              const float* __restrict__ W2,
                                              const float* __restrict__ out1,
                                              float* __restrict__ part2)
{
    __shared__ float xs[CC][8][8];      // 4.6 KB
    __shared__ float red[2][4][8][32];  // 8 KB (dbuf)
    __shared__ float ccs[2][8][32];     // 2 KB (dbuf)

    const int tid = threadIdx.x;
    const int f  = tid & 31;
    const int og = tid >> 5;            // 0..7
    const int o0 = 2*og, o1 = o0 + 1;
    const int wv = tid >> 6;            // wave 0..3
    const int half = (tid >> 5) & 1;    // og parity within wave
    const int ch = blockIdx.x & (CH-1);
    const int pg = blockIdx.x >> 4;     // 0..71

    stage_x(x, xs, ch, pg, tid);

    // out1 values for (f, o0/o1) per position
    float u0[8], u1[8];
    #pragma unroll
    for (int p = 0; p < 8; ++p) {
        const float* up = out1 + (size_t)(pg*8 + p)*512 + f*DO;
        u0[p] = up[o0];
        u1[p] = up[o1];
    }

    const float4* W2f4 = (const float4*)W2;
    float acc0[8], acc1[8];
    #pragma unroll
    for (int p = 0; p < 8; ++p) { acc0[p] = 0.f; acc1[p] = 0.f; }

    __syncthreads();

    #pragma unroll 1
    for (int cl = 0; cl < CC; ++cl) {
        const int c = ch*CC + cl;
        const int buf = cl & 1;
        const float4* wp = W2f4 + (size_t)c*1024 + f*2;
        const float4 w00 = wp[o0*64], w01 = wp[o0*64 + 1];
        const float4 w10 = wp[o1*64], w11 = wp[o1*64 + 1];

        float pred0[8], pred1[8];
        #pragma unroll
        for (int p = 0; p < 8; ++p) {
            const float4 a  = *(const float4*)&xs[cl][p][0];
            const float4 bq = *(const float4*)&xs[cl][p][4];
            pred0[p] = dot8f(w00, w01, a, bq);
            pred1[p] = dot8f(w10, w11, a, bq);
        }

        // agr partial over this thread's two o's; combine og-pairs via xor-32
        #pragma unroll
        for (int p = 0; p < 8; ++p) {
            float ap = pred0[p]*u0[p] + pred1[p]*u1[p];
            ap += __shfl_xor(ap, 32);
            if (half == 0) red[buf][wv][p][f] = ap;
        }
        __syncthreads();

        // remapped role: (p2, f2); finish f-sum, softmax over f, publish cc
        {
            const int p2 = tid >> 5, f2 = tid & 31;
            const float agr = red[buf][0][p2][f2] + red[buf][1][p2][f2]
                            + red[buf][2][p2][f2] + red[buf][3][p2][f2];
            float m = agr;
            m = fmaxf(m, __shfl_xor(m, 1));
            m = fmaxf(m, __shfl_xor(m, 2));
            m = fmaxf(m, __shfl_xor(m, 4));
            m = fmaxf(m, __shfl_xor(m, 8));
            m = fmaxf(m, __shfl_xor(m, 16));
            const float e = __expf(agr - m);
            float s = e;
            s += __shfl_xor(s, 1);
            s += __shfl_xor(s, 2);
            s += __shfl_xor(s, 4);
            s += __shfl_xor(s, 8);
            s += __shfl_xor(s, 16);
            ccs[buf][p2][f2] = e / s;
        }
        __syncthreads();

        // back to (f, og): accumulate cent2
        #pragma unroll
        for (int p = 0; p < 8; ++p) {
            const float cv = ccs[buf][p][f];
            acc0[p] += cv*pred0[p];
            acc1[p] += cv*pred1[p];
        }
    }

    #pragma unroll
    for (int p = 0; p < 8; ++p) {
        const size_t base = ((size_t)(ch*NPOS + pg*8 + p))*DO;
        part2[(base + o0)*F + f] = acc0[p];
        part2[(base + o1)*F + f] = acc1[p];
    }
}

// ---- kern3: reduce cent2 partials ([ch][pos][o][f]), squash, store. -----------
__global__ __launch_bounds__(256) void kern3(const float* __restrict__ part2,
                                             float* __restrict__ out)
{
    const int tid = threadIdx.x;
    const int f = tid & 31, p = tid >> 5;
    const int pos = blockIdx.x*8 + p;

    float cent[DO];
    #pragma unroll
    for (int o = 0; o < DO; ++o) cent[o] = 0.f;
    #pragma unroll 1
    for (int k = 0; k < CH; ++k) {
        const float* s = part2 + (size_t)(k*NPOS + pos)*512 + f;
        #pragma unroll
        for (int o = 0; o < DO; ++o) cent[o] += s[o*F];
    }
    float sn = 0.f;
    #pragma unroll
    for (int o = 0; o < DO; ++o) sn += cent[o]*cent[o];
    const float sc = (sn/(1.f + sn)) * rsqrtf(sn + EPS);
    float* dst = out + ((size_t)pos*F + f)*DO;
    #pragma unroll
    for (int o = 0; o < DO; ++o) dst[o] = cent[o]*sc;
}

// -------- fp32 single-kernel fallback (if ws too small) ------------------------
__device__ __forceinline__ float dot8(const float4* __restrict__ w,
                                      const float4 p0, const float4 p1) {
    float4 a = w[0], b = w[1];
    return a.x*p0.x + a.y*p0.y + a.z*p0.z + a.w*p0.w
         + b.x*p1.x + b.y*p1.y + b.z*p1.z + b.w*p1.w;
}

__global__ __launch_bounds__(256) void capsule_kernel_f32(
    const float* __restrict__ x, const float* __restrict__ Wt,
    float* __restrict__ out)
{
    __shared__ float patch[C*DI];
    __shared__ float cent[F*DO];
    __shared__ float out1[F*DO];
    __shared__ float agr[F*C];
    __shared__ float scale_s[F];

    const int tid = threadIdx.x;
    const int pos = blockIdx.x;
    const int b   = pos / (HO*WO);
    const int rem = pos % (HO*WO);
    const int ho  = rem / WO;
    const int wo  = rem % WO;

    #pragma unroll
    for (int slab = 0; slab < 9; ++slab) {
        const int kh = slab / 3, kw = slab % 3;
        const float* src = x + (((b*H_IN + ho + kh)*W_IN + (wo + kw))*FIN)*DI;
        patch[slab*256 + tid] = src[tid];
    }
    __syncthreads();

    const float4* pv = (const float4*)patch;

    {
        const int fo0 = tid, fo1 = tid + 256;
        const int f0 = fo0 >> 4, o0 = fo0 & 15;
        const int f1 = fo1 >> 4, o1 = fo1 & 15;
        float acc0 = 0.f, acc1 = 0.f;
        for (int c = 0; c < C; ++c) {
            const float4 p0 = pv[c*2], p1 = pv[c*2+1];
            acc0 += dot8((const float4*)(Wt + ((f0*C + c)*DO + o0)*DI), p0, p1);
            acc1 += dot8((const float4*)(Wt + ((f1*C + c)*DO + o1)*DI), p0, p1);
        }
        cent[fo0] = acc0 * (1.f/32.f);
        cent[fo1] = acc1 * (1.f/32.f);
    }
    __syncthreads();

    if (tid < F) {
        float sn = 0.f;
        #pragma unroll
        for (int o = 0; o < DO; ++o) { float v = cent[tid*DO + o]; sn += v*v; }
        const float sc = (sn/(1.f + sn)) * rsqrtf(sn + EPS);
        #pragma unroll
        for (int o = 0; o < DO; ++o) out1[tid*DO + o] = cent[tid*DO + o] * sc;
    }
    __syncthreads();

    #pragma unroll 1
    for (int r = 0; r < (F*C)/256; ++r) {
        const int pp = tid + 256*r;
        const int f = pp / C, c = pp % C;
        const float4* wrow = (const float4*)(Wt + (f*C + c)*DO*DI);
        const float4 p0 = pv[c*2], p1 = pv[c*2+1];
        float a = 0.f;
        #pragma unroll
        for (int o = 0; o < DO; ++o) a += dot8(wrow + o*2, p0, p1) * out1[f*DO + o];
        agr[pp] = a;
    }
    __syncthreads();

    for (int c = tid; c < C; c += 256) {
        float m = -1e30f;
        #pragma unroll
        for (int f = 0; f < F; ++f) m = fmaxf(m, agr[f*C + c]);
        float s = 0.f;
        #pragma unroll
        for (int f = 0; f < F; ++f) {
            const float e = __expf(agr[f*C + c] - m);
            agr[f*C + c] = e; s += e;
        }
        const float inv = 1.f / s;
        #pragma unroll
        for (int f = 0; f < F; ++f) agr[f*C + c] *= inv;
    }
    __syncthreads();

    {
        const int fo0 = tid, fo1 = tid + 256;
        const int f0 = fo0 >> 4, o0 = fo0 & 15;
        const int f1 = fo1 >> 4, o1 = fo1 & 15;
        float acc0 = 0.f, acc1 = 0.f;
        for (int c = 0; c < C; ++c) {
            const float4 p0 = pv[c*2], p1 = pv[c*2+1];
            acc0 += agr[f0*C + c] * dot8((const float4*)(Wt + ((f0*C + c)*DO + o0)*DI), p0, p1);
            acc1 += agr[f1*C + c] * dot8((const float4*)(Wt + ((f1*C + c)*DO + o1)*DI), p0, p1);
        }
        cent[fo0] = acc0;
        cent[fo1] = acc1;
    }
    __syncthreads();

    if (tid < F) {
        float sn = 0.f;
        #pragma unroll
        for (int o = 0; o < DO; ++o) { float v = cent[tid*DO + o]; sn += v*v; }
        scale_s[tid] = (sn/(1.f + sn)) * rsqrtf(sn + EPS);
    }
    __syncthreads();

    out[pos*(F*DO) + tid]       = cent[tid]       * scale_s[tid >> 4];
    out[pos*(F*DO) + tid + 256] = cent[tid + 256] * scale_s[(tid >> 4) + 16];
}

extern "C" void kernel_launch(void* const* d_in, const int* in_sizes, int n_in,
                              void* d_out, int out_size, void* d_ws, size_t ws_size,
                              hipStream_t stream) {
    const float* x  = (const float*)d_in[0];
    const float* Wt = (const float*)d_in[1];
    float* out = (float*)d_out;

    if (ws_size >= W2_BYTES + PART_BYTES + OUT1_BYTES) {
        float* W2    = (float*)d_ws;
        float* part1 = (float*)((char*)d_ws + W2_BYTES);      // part2 aliases part1
        float* out1  = (float*)((char*)d_ws + W2_BYTES + PART_BYTES);
        kernT<<<(F*C*DO*DI)/4/256, 256, 0, stream>>>(Wt, W2);         // 1152 blocks
        kern1n<<<CH*(NPOS/8), 256, 0, stream>>>(x, W2, part1);        // 1152 blocks
        kernO<<<NPOS, 512, 0, stream>>>(part1, out1);                 // 576 blocks
        kern2n<<<CH*(NPOS/8), 256, 0, stream>>>(x, W2, out1, part1);  // 1152 blocks
        kern3<<<NPOS/8, 256, 0, stream>>>(part1, out);                // 72 blocks
    } else {
        capsule_kernel_f32<<<NPOS, 256, 0, stream>>>(x, Wt, out);
    }
}